// Round 1
// baseline (235.831 us; speedup 1.0000x reference)
//
#include <hip/hip_runtime.h>

#define EPS_F 1e-5f

// Output layout (floats):
//   [0, 2700)                : ref3d  (1,900,3)  = reference_points copy
//   [2700, 2700+5529600)     : sampled_feats (1,256,900,6,1,4)
//                              idx = 2700 + c*21600 + q*24 + n*4 + l
//   [5532300, 5537700)       : mask (1,1,900,6,1,1), idx = 5532300 + q*6 + n
//
// Grid: 5400 blocks = (q,n) pairs; 256 threads = channel c.
// Projection is block-uniform -> uniform branches, scalar loads for params.
__global__ __launch_bounds__(256) void fs_kernel(
    const float* __restrict__ f0, const float* __restrict__ f1,
    const float* __restrict__ f2, const float* __restrict__ f3,
    const float* __restrict__ ref_pts, const float* __restrict__ pc_range,
    const float* __restrict__ img_shape, const float* __restrict__ l2i,
    float* __restrict__ out)
{
    const int bid = blockIdx.x;
    const int n = bid % 6;          // camera
    const int q = bid / 6;          // query
    const int c = threadIdx.x;      // channel

    // ---- projection (uniform across block) ----
    const float X = ref_pts[q * 3 + 0] * (pc_range[3] - pc_range[0]) + pc_range[0];
    const float Y = ref_pts[q * 3 + 1] * (pc_range[4] - pc_range[1]) + pc_range[1];
    const float Z = ref_pts[q * 3 + 2] * (pc_range[5] - pc_range[2]) + pc_range[2];
    const float* M = l2i + n * 16;
    const float cx = M[0] * X + M[1] * Y + M[2]  * Z + M[3];
    const float cy = M[4] * X + M[5] * Y + M[6]  * Z + M[7];
    const float cz = M[8] * X + M[9] * Y + M[10] * Z + M[11];
    const float denom = fmaxf(cz, EPS_F);
    const float u = (cx / denom) / img_shape[1];   // x / 1600
    const float v = (cy / denom) / img_shape[0];   // y / 928
    const float xn = (u - 0.5f) * 2.0f;
    const float yn = (v - 0.5f) * 2.0f;

    // ---- mask output (one lane) ----
    if (threadIdx.x == 0) {
        const bool m = (cz > EPS_F) && (xn > -1.0f) && (xn < 1.0f)
                                    && (yn > -1.0f) && (yn < 1.0f);
        out[5532300 + q * 6 + n] = m ? 1.0f : 0.0f;
    }
    // ---- ref3d copy (3 lanes of the n==0 block for this q) ----
    if (n == 0 && threadIdx.x < 3) {
        out[q * 3 + threadIdx.x] = ref_pts[q * 3 + threadIdx.x];
    }

    const float* const feats[4] = {f0, f1, f2, f3};
    const int Hs[4] = {116, 58, 29, 15};
    const int Ws[4] = {200, 100, 50, 25};

    float acc[4];
    #pragma unroll
    for (int l = 0; l < 4; ++l) {
        const int W = Ws[l];
        const int H = Hs[l];
        // align_corners=False mapping (mirror reference op order)
        const float ix = ((xn + 1.0f) * (float)W - 1.0f) * 0.5f;
        const float iy = ((yn + 1.0f) * (float)H - 1.0f) * 0.5f;
        const float ix0f = floorf(ix);
        const float iy0f = floorf(iy);
        const float wx1 = ix - ix0f, wx0 = 1.0f - wx1;
        const float wy1 = iy - iy0f, wy0 = 1.0f - wy1;
        const bool vx0 = (ix0f >= 0.0f)  && (ix0f <= (float)(W - 1));
        const bool vx1 = (ix0f >= -1.0f) && (ix0f <= (float)(W - 2));
        const bool vy0 = (iy0f >= 0.0f)  && (iy0f <= (float)(H - 1));
        const bool vy1 = (iy0f >= -1.0f) && (iy0f <= (float)(H - 2));

        float val = 0.0f;
        if ((vx0 || vx1) && (vy0 || vy1)) {   // uniform branch
            // safe int conversion: ix0f in [-1, W-1], iy0f in [-1, H-1] here
            const int x0 = (int)ix0f;
            const int x1 = x0 + 1;            // ==0 when only vx1 (ix0f==-1)
            const float* base = feats[l] + (size_t)(n * 256 + c) * (size_t)(H * W);
            if (vy0) {
                const float* row = base + (int)iy0f * W;
                float r = 0.0f;
                if (vx0) r += wx0 * row[x0];
                if (vx1) r += wx1 * row[x1];
                val += wy0 * r;
            }
            if (vy1) {
                const float* row = base + ((int)iy0f + 1) * W;
                float r = 0.0f;
                if (vx0) r += wx0 * row[x0];
                if (vx1) r += wx1 * row[x1];
                val += wy1 * r;
            }
        }
        acc[l] = val;
    }

    // ---- sampled_feats write: 16B contiguous per thread (l innermost) ----
    float4 o;
    o.x = acc[0]; o.y = acc[1]; o.z = acc[2]; o.w = acc[3];
    *(float4*)(out + 2700 + (size_t)c * 21600 + q * 24 + n * 4) = o;
}

extern "C" void kernel_launch(void* const* d_in, const int* in_sizes, int n_in,
                              void* d_out, int out_size, void* d_ws, size_t ws_size,
                              hipStream_t stream) {
    const float* f0  = (const float*)d_in[0];  // (1,6,256,116,200)
    const float* f1  = (const float*)d_in[1];  // (1,6,256,58,100)
    const float* f2  = (const float*)d_in[2];  // (1,6,256,29,50)
    const float* f3  = (const float*)d_in[3];  // (1,6,256,15,25)
    const float* rp  = (const float*)d_in[4];  // (1,900,3)
    const float* pcr = (const float*)d_in[5];  // (6,)
    const float* ish = (const float*)d_in[6];  // (2,)
    const float* l2i = (const float*)d_in[7];  // (1,6,4,4)
    float* out = (float*)d_out;

    fs_kernel<<<5400, 256, 0, stream>>>(f0, f1, f2, f3, rp, pcr, ish, l2i, out);
}